// Round 16
// baseline (146.280 us; speedup 1.0000x reference)
//
#include <hip/hip_runtime.h>
#include <hip/hip_bf16.h>

#define NN 10000
#define MP 10112        // 79*128 padded M
#define RR 16
#define NBASE 30
#define EE 160000
#define HIDF 256
#define OUTF 128
#define NSEG (NN * RR)

typedef __attribute__((ext_vector_type(8))) short bf16x8;
typedef __attribute__((ext_vector_type(4))) short s16x4;
typedef __attribute__((ext_vector_type(4))) float f32x4;

static __device__ __forceinline__ short f2bf(float f) {
    union { float f; unsigned u; } v; v.f = f;
    unsigned r = v.u + 0x7FFFu + ((v.u >> 16) & 1u);
    return (short)(r >> 16);
}
static __device__ __forceinline__ float bf2f(short s) {
    union { unsigned u; float f; } v;
    v.u = ((unsigned)(unsigned short)s) << 16;
    return v.f;
}
static __device__ __forceinline__ void gl16(const short* g, short* l) {
    __builtin_amdgcn_global_load_lds((const __attribute__((address_space(1))) void*)g,
                                     (__attribute__((address_space(3))) void*)l, 16, 0, 0);
}

// ---- custom zero (replaces hipMemsetAsync; r15 profile showed 43us fill) ----
__global__ void zero_k(int* __restrict__ p, int n4) {
    int i = blockIdx.x * 256 + threadIdx.x;
    if (i < n4) ((int4*)p)[i] = make_int4(0, 0, 0, 0);
}

// ---- weight build: WT[n][i] bf16, n = r*OUT + o (r==16 -> root), stride 256 ----
template <int OUT>
__global__ void wtr_k(const float* __restrict__ basis, const float* __restrict__ comp,
                      const float* __restrict__ root, short* __restrict__ WT) {
    __shared__ short t[32][34];
    const int i0 = blockIdx.x * 32, n0 = blockIdx.y * 32;
    const int r = n0 / OUT, o0 = n0 % OUT;
    const int tx = threadIdx.x & 31, ty = threadIdx.x >> 5;  // ty 0..7
    #pragma unroll
    for (int dy = 0; dy < 32; dy += 8) {
        const int i = i0 + ty + dy, o = o0 + tx;
        float v;
        if (r < RR) {
            float s = 0.f;
            #pragma unroll
            for (int b = 0; b < NBASE; b++)
                s += comp[r * NBASE + b] * basis[((long)b * 256 + i) * OUT + o];
            v = s;
        } else {
            v = root[(long)i * OUT + o];
        }
        t[ty + dy][tx] = f2bf(v);
    }
    __syncthreads();
    #pragma unroll
    for (int dy = 0; dy < 32; dy += 8)
        WT[(long)(n0 + ty + dy) * 256 + i0 + tx] = t[tx][ty + dy];
}

// ---- fused: X->bf16 convert (blocks 0..2499) + edge count (blocks 2500..3124) ----
__global__ void count_cvt_k(const float* __restrict__ X, short* __restrict__ Y,
                            const int* __restrict__ dst, const int* __restrict__ et,
                            int* __restrict__ cnt, int* __restrict__ deg) {
    int b = blockIdx.x;
    if (b < 2500) {
        int i = b * 256 + threadIdx.x;  // < NN*64
        float4 v = *(const float4*)(X + (long)i * 4);
        s16x4 pk = { f2bf(v.x), f2bf(v.y), f2bf(v.z), f2bf(v.w) };
        *(s16x4*)&Y[(long)i * 4] = pk;
    } else {
        int e = (b - 2500) * 256 + threadIdx.x;
        if (e < EE) {
            int d = dst[e];
            atomicAdd(&cnt[d * RR + et[e]], 1);
            atomicAdd(&deg[d], 1);
        }
    }
}

// ---- node-level scan (NN=10000 elements, 16x smaller than segment scan) ----
__global__ void scan1_k(const int* __restrict__ deg, int* __restrict__ incl,
                        int* __restrict__ bsum) {
    __shared__ int s[256];
    int i = blockIdx.x * 256 + threadIdx.x;
    int v = (i < NN) ? deg[i] : 0;
    s[threadIdx.x] = v;
    __syncthreads();
    for (int off = 1; off < 256; off <<= 1) {
        int u = (threadIdx.x >= off) ? s[threadIdx.x - off] : 0;
        __syncthreads();
        s[threadIdx.x] += u;
        __syncthreads();
    }
    if (i < NN) incl[i] = s[threadIdx.x];
    if (threadIdx.x == 255) bsum[blockIdx.x] = s[255];
}

__global__ void scan2_k(int* __restrict__ bsum, int nb) {
    __shared__ int s[1024];
    int t = threadIdx.x;
    s[t] = (t < nb) ? bsum[t] : 0;
    __syncthreads();
    for (int off = 1; off < 1024; off <<= 1) {
        int u = (t >= off) ? s[t - off] : 0;
        __syncthreads();
        s[t] += u;
        __syncthreads();
    }
    if (t < nb) bsum[t] = s[t];
}

__global__ void scan3_k(const int* __restrict__ deg, const int* __restrict__ incl,
                        const int* __restrict__ bsum, int* __restrict__ rowp,
                        int* __restrict__ fillpos) {
    int i = blockIdx.x * 256 + threadIdx.x;
    if (i >= NN) return;
    int off = (blockIdx.x > 0) ? bsum[blockIdx.x - 1] : 0;
    int ex = off + incl[i] - deg[i];
    rowp[i] = ex;
    fillpos[i] = ex;
    if (i == 0) rowp[NN] = EE;
}

// per-edge: node-grouped slice offsets + mean weight (1/cnt computed here; invc pass deleted)
__global__ void fill_k(const int* __restrict__ src, const int* __restrict__ dst,
                       const int* __restrict__ et, int* __restrict__ fillpos,
                       const int* __restrict__ cnt,
                       int* __restrict__ eoff1, int* __restrict__ eoff2,
                       float* __restrict__ wgt) {
    int e = blockIdx.x * 256 + threadIdx.x;
    if (e < EE) {
        int s = src[e], t = et[e], d = dst[e];
        int p = atomicAdd(&fillpos[d], 1);
        eoff1[p] = s * (17 * HIDF) + t * HIDF;
        eoff2[p] = s * (17 * OUTF) + t * OUTF;
        wgt[p] = 1.0f / (float)cnt[d * RR + t];
    }
}

// ---- dense GEMM: XW[m][n] = sum_k A[m][k] * WT[n][k], K=256, bf16 out ----
// 128x64 tiles, BK=64, 4 waves as 2x2 (64x32 each), single-buffer 24 KB LDS,
// 6 blocks/CU. m-major XCD swizzle; XOR swizzle both sides (slot s^(r&7));
// LDS-restaged coalesced epilogue (stride 68). [r15-identical]
template <int NTOT>
__global__ __launch_bounds__(256, 6) void gemm_xw_k(const short* __restrict__ A,
                                                    const short* __restrict__ WT,
                                                    short* __restrict__ XW) {
    constexpr int NBN = NTOT / 64;
    __shared__ __align__(16) short smem[12288];  // As[0..8191], Bs[8192..12287]

    const int nwg = gridDim.x;
    const int q = nwg >> 3, r = nwg & 7;
    const int orig = blockIdx.x;
    const int xcd = orig & 7, wi = orig >> 3;
    const int wgid = (xcd < r ? xcd * (q + 1) : r * (q + 1) + (xcd - r) * q) + wi;
    const int m0 = (wgid / NBN) * 128;
    const int n0 = (wgid % NBN) * 64;

    const int tid = threadIdx.x;
    const int lane = tid & 63;
    const int w = tid >> 6;
    const int wr = w >> 1, wc = w & 1;
    const int al = lane & 15;
    const int cl = lane >> 4;

    int gsrcA[4];
    #pragma unroll
    for (int i = 0; i < 4; i++) {
        int ci = i * 256 + tid;
        int row = ci >> 3;
        gsrcA[i] = row * 256 + (((ci & 7) ^ (row & 7)) << 3);
    }
    int gsrcB[2];
    #pragma unroll
    for (int i = 0; i < 2; i++) {
        int ci = i * 256 + tid;
        int row = ci >> 3;
        gsrcB[i] = row * 256 + (((ci & 7) ^ (row & 7)) << 3);
    }

    int aoff[4][2], boff[2][2];
    #pragma unroll
    for (int f = 0; f < 4; f++)
        #pragma unroll
        for (int k2 = 0; k2 < 2; k2++) {
            int ra = wr * 64 + f * 16 + al;
            aoff[f][k2] = (ra << 6) + ((((k2 << 2) | cl) ^ (ra & 7)) << 3);
        }
    #pragma unroll
    for (int f = 0; f < 2; f++)
        #pragma unroll
        for (int k2 = 0; k2 < 2; k2++) {
            int rb = wc * 32 + f * 16 + al;
            boff[f][k2] = (rb << 6) + ((((k2 << 2) | cl) ^ (rb & 7)) << 3);
        }

    f32x4 acc[4][2] = {};
    const short* abase = A + (long)m0 * 256;
    const short* bbase = WT + (long)n0 * 256;

    #pragma unroll
    for (int kk = 0; kk < 256; kk += 64) {
        #pragma unroll
        for (int i = 0; i < 4; i++)
            gl16(abase + kk + gsrcA[i], &smem[i * 2048 + w * 512]);
        #pragma unroll
        for (int i = 0; i < 2; i++)
            gl16(bbase + kk + gsrcB[i], &smem[8192 + i * 2048 + w * 512]);
        __syncthreads();

        bf16x8 a[4][2], b[2][2];
        #pragma unroll
        for (int f = 0; f < 4; f++)
            #pragma unroll
            for (int k2 = 0; k2 < 2; k2++)
                a[f][k2] = *(const bf16x8*)&smem[aoff[f][k2]];
        #pragma unroll
        for (int f = 0; f < 2; f++)
            #pragma unroll
            for (int k2 = 0; k2 < 2; k2++)
                b[f][k2] = *(const bf16x8*)&smem[8192 + boff[f][k2]];
        #pragma unroll
        for (int k2 = 0; k2 < 2; k2++)
            #pragma unroll
            for (int fm = 0; fm < 4; fm++)
                #pragma unroll
                for (int fn = 0; fn < 2; fn++)
                    acc[fm][fn] = __builtin_amdgcn_mfma_f32_16x16x32_bf16(
                        a[fm][k2], b[fn][k2], acc[fm][fn], 0, 0, 0);
        __syncthreads();
    }

    #pragma unroll
    for (int fm = 0; fm < 4; fm++) {
        const int rowb = wr * 64 + fm * 16 + (cl << 2);
        #pragma unroll
        for (int fn = 0; fn < 2; fn++) {
            const int col = wc * 32 + fn * 16 + al;
            #pragma unroll
            for (int j = 0; j < 4; j++)
                smem[(rowb + j) * 68 + col] = f2bf(acc[fm][fn][j]);
        }
    }
    __syncthreads();

    #pragma unroll
    for (int pass = 0; pass < 4; pass++) {
        int c = pass * 256 + tid;
        int row = c >> 3, qq = c & 7;
        uint4 v = *(const uint4*)&smem[row * 68 + qq * 8];
        *(uint4*)&XW[(long)(m0 + row) * NTOT + n0 + qq * 8] = v;
    }
}

// ---- per-node aggregate: out[n] = sum_edges wgt*XW[eoff] + XW[n,root] + bias ----
// one wave per node; node-grouped edges via rowp[n]..rowp[n+1]; 4-way unrolled.
template <int OUT, bool L1>
__global__ void aggh_k(const int* __restrict__ rowp, const int* __restrict__ eoff,
                       const float* __restrict__ wgt, const short* __restrict__ XW,
                       const float* __restrict__ bias, short* __restrict__ Hout,
                       float* __restrict__ Fout) {
    constexpr int NTOT = 17 * OUT;
    const int n = (blockIdx.x * 256 + threadIdx.x) >> 6;
    const int lane = threadIdx.x & 63;
    if (n >= NN) return;
    const int b = rowp[n], e = rowp[n + 1];

    if (L1) {
        float a0 = 0.f, a1 = 0.f, a2 = 0.f, a3 = 0.f;
        int j = b;
        for (; j + 3 < e; j += 4) {   // 4-way unroll: 4 gathers in flight
            s16x4 v0 = *(const s16x4*)&XW[(long)eoff[j] + lane * 4];
            s16x4 v1 = *(const s16x4*)&XW[(long)eoff[j + 1] + lane * 4];
            s16x4 v2 = *(const s16x4*)&XW[(long)eoff[j + 2] + lane * 4];
            s16x4 v3 = *(const s16x4*)&XW[(long)eoff[j + 3] + lane * 4];
            float w0 = wgt[j], w1 = wgt[j + 1], w2 = wgt[j + 2], w3 = wgt[j + 3];
            a0 += w0 * bf2f(v0.x) + w1 * bf2f(v1.x) + w2 * bf2f(v2.x) + w3 * bf2f(v3.x);
            a1 += w0 * bf2f(v0.y) + w1 * bf2f(v1.y) + w2 * bf2f(v2.y) + w3 * bf2f(v3.y);
            a2 += w0 * bf2f(v0.z) + w1 * bf2f(v1.z) + w2 * bf2f(v2.z) + w3 * bf2f(v3.z);
            a3 += w0 * bf2f(v0.w) + w1 * bf2f(v1.w) + w2 * bf2f(v2.w) + w3 * bf2f(v3.w);
        }
        for (; j < e; j++) {
            int o0 = eoff[j]; float w0 = wgt[j];
            s16x4 v0 = *(const s16x4*)&XW[(long)o0 + lane * 4];
            a0 += w0 * bf2f(v0.x); a1 += w0 * bf2f(v0.y);
            a2 += w0 * bf2f(v0.z); a3 += w0 * bf2f(v0.w);
        }
        s16x4 rt = *(const s16x4*)&XW[(long)n * NTOT + 16 * OUT + lane * 4];
        f32x4 bb = *(const f32x4*)&bias[lane * 4];
        a0 = fmaxf(a0 + bf2f(rt.x) + bb.x, 0.f);
        a1 = fmaxf(a1 + bf2f(rt.y) + bb.y, 0.f);
        a2 = fmaxf(a2 + bf2f(rt.z) + bb.z, 0.f);
        a3 = fmaxf(a3 + bf2f(rt.w) + bb.w, 0.f);
        s16x4 pk = { f2bf(a0), f2bf(a1), f2bf(a2), f2bf(a3) };
        *(s16x4*)&Hout[(long)n * OUT + lane * 4] = pk;
    } else {
        float a0 = 0.f, a1 = 0.f;
        int j = b;
        for (; j + 3 < e; j += 4) {
            unsigned v0 = *(const unsigned*)&XW[(long)eoff[j] + lane * 2];
            unsigned v1 = *(const unsigned*)&XW[(long)eoff[j + 1] + lane * 2];
            unsigned v2 = *(const unsigned*)&XW[(long)eoff[j + 2] + lane * 2];
            unsigned v3 = *(const unsigned*)&XW[(long)eoff[j + 3] + lane * 2];
            float w0 = wgt[j], w1 = wgt[j + 1], w2 = wgt[j + 2], w3 = wgt[j + 3];
            a0 += w0 * bf2f((short)(v0 & 0xffff)) + w1 * bf2f((short)(v1 & 0xffff))
                + w2 * bf2f((short)(v2 & 0xffff)) + w3 * bf2f((short)(v3 & 0xffff));
            a1 += w0 * bf2f((short)(v0 >> 16)) + w1 * bf2f((short)(v1 >> 16))
                + w2 * bf2f((short)(v2 >> 16)) + w3 * bf2f((short)(v3 >> 16));
        }
        for (; j < e; j++) {
            int o0 = eoff[j]; float w0 = wgt[j];
            unsigned v0 = *(const unsigned*)&XW[(long)o0 + lane * 2];
            a0 += w0 * bf2f((short)(v0 & 0xffff));
            a1 += w0 * bf2f((short)(v0 >> 16));
        }
        unsigned rt = *(const unsigned*)&XW[(long)n * NTOT + 16 * OUT + lane * 2];
        a0 += bf2f((short)(rt & 0xffff)) + bias[lane * 2];
        a1 += bf2f((short)(rt >> 16)) + bias[lane * 2 + 1];
        float2 st = { a0, a1 };
        *(float2*)&Fout[(long)n * OUT + lane * 2] = st;
    }
}

extern "C" void kernel_launch(void* const* d_in, const int* in_sizes, int n_in,
                              void* d_out, int out_size, void* d_ws, size_t ws_size,
                              hipStream_t stream) {
    const float* x      = (const float*)d_in[0];
    const int*   ei     = (const int*)d_in[1];
    const int*   et     = (const int*)d_in[2];
    const float* basis1 = (const float*)d_in[3];
    const float* comp1  = (const float*)d_in[4];
    const float* root1  = (const float*)d_in[5];
    const float* bias1  = (const float*)d_in[6];
    const float* basis2 = (const float*)d_in[7];
    const float* comp2  = (const float*)d_in[8];
    const float* root2  = (const float*)d_in[9];
    const float* bias2  = (const float*)d_in[10];
    const int* src = ei;
    const int* dst = ei + EE;

    char* p = (char*)d_ws;
    auto take = [&](size_t bytes) { char* q = p; p += (bytes + 255) & ~(size_t)255; return q; };
    short* XW    = (short*)take((size_t)MP * 17 * HIDF * 2); // 88 MB (layer2 reuses)
    short* WT1   = (short*)take((size_t)17 * HIDF * 256 * 2);// 2.23 MB
    short* WT2   = (short*)take((size_t)17 * OUTF * 256 * 2);// 1.11 MB
    short* Xbf   = (short*)take((size_t)MP * 256 * 2);       // 5.18 MB
    short* Hbf   = (short*)take((size_t)MP * 256 * 2);       // 5.18 MB
    int*   cnt   = (int*)take((size_t)(NSEG + NN) * 4);      // cnt[NSEG] + deg[NN], zeroed together
    int*   deg   = cnt + NSEG;
    int*   incl  = (int*)take((size_t)NN * 4);
    int*   rowp  = (int*)take((size_t)(NN + 1) * 4);
    int*   fpos  = (int*)take((size_t)NN * 4);
    int*   bsum  = (int*)take(1024 * 4);
    int*   eoff1 = (int*)take((size_t)EE * 4);
    int*   eoff2 = (int*)take((size_t)EE * 4);
    float* wgt   = (float*)take((size_t)EE * 4);

    // zero cnt+deg (custom kernel; hipMemsetAsync showed 43us in r15 profile)
    zero_k<<<((NSEG + NN) / 4 + 255) / 256, 256, 0, stream>>>(cnt, (NSEG + NN) / 4);

    // weights
    {
        dim3 g1(256 / 32, 17 * HIDF / 32), g2(256 / 32, 17 * OUTF / 32);
        wtr_k<HIDF><<<g1, 256, 0, stream>>>(basis1, comp1, root1, WT1);
        wtr_k<OUTF><<<g2, 256, 0, stream>>>(basis2, comp2, root2, WT2);
    }

    // fused X->bf16 + edge count; then node-level CSR
    count_cvt_k<<<2500 + (EE + 255) / 256, 256, 0, stream>>>(x, Xbf, dst, et, cnt, deg);
    scan1_k<<<(NN + 255) / 256, 256, 0, stream>>>(deg, incl, bsum);
    scan2_k<<<1, 1024, 0, stream>>>(bsum, (NN + 255) / 256);
    scan3_k<<<(NN + 255) / 256, 256, 0, stream>>>(deg, incl, bsum, rowp, fpos);
    fill_k<<<(EE + 255) / 256, 256, 0, stream>>>(src, dst, et, fpos, cnt, eoff1, eoff2, wgt);

    // layer 1: XW = X @ [W_r..., root]  (grid 79*68 = 5372), then per-node agg
    gemm_xw_k<17 * HIDF><<<(MP / 128) * (17 * HIDF / 64), 256, 0, stream>>>(Xbf, WT1, XW);
    aggh_k<HIDF, true><<<(NN * 64) / 256, 256, 0, stream>>>(rowp, eoff1, wgt, XW, bias1, Hbf, nullptr);

    // layer 2: XW2 = H @ [W_r..., root]  (grid 79*34 = 2686), then per-node agg
    gemm_xw_k<17 * OUTF><<<(MP / 128) * (17 * OUTF / 64), 256, 0, stream>>>(Hbf, WT2, XW);
    aggh_k<OUTF, false><<<(NN * 64) / 256, 256, 0, stream>>>(rowp, eoff2, wgt, XW, bias2, nullptr, (float*)d_out);
}

// Round 17
// 135.014 us; speedup vs baseline: 1.0834x; 1.0834x over previous
//
#include <hip/hip_runtime.h>
#include <hip/hip_bf16.h>

#define NN 10000
#define MP 10112        // 79*128 padded M
#define RR 16
#define NBASE 30
#define EE 160000
#define HIDF 256
#define OUTF 128
#define NSEG (NN * RR)

typedef __attribute__((ext_vector_type(8))) short bf16x8;
typedef __attribute__((ext_vector_type(4))) short s16x4;
typedef __attribute__((ext_vector_type(4))) float f32x4;

static __device__ __forceinline__ short f2bf(float f) {
    union { float f; unsigned u; } v; v.f = f;
    unsigned r = v.u + 0x7FFFu + ((v.u >> 16) & 1u);
    return (short)(r >> 16);
}
static __device__ __forceinline__ float bf2f(short s) {
    union { unsigned u; float f; } v;
    v.u = ((unsigned)(unsigned short)s) << 16;
    return v.f;
}
static __device__ __forceinline__ void gl16(const short* g, short* l) {
    __builtin_amdgcn_global_load_lds((const __attribute__((address_space(1))) void*)g,
                                     (__attribute__((address_space(3))) void*)l, 16, 0, 0);
}

// ---- weight build: WT[n][i] bf16, n = r*OUT + o (r==16 -> root), stride 256 ----
template <int OUT>
__global__ void wtr_k(const float* __restrict__ basis, const float* __restrict__ comp,
                      const float* __restrict__ root, short* __restrict__ WT) {
    __shared__ short t[32][34];
    const int i0 = blockIdx.x * 32, n0 = blockIdx.y * 32;
    const int r = n0 / OUT, o0 = n0 % OUT;
    const int tx = threadIdx.x & 31, ty = threadIdx.x >> 5;  // ty 0..7
    #pragma unroll
    for (int dy = 0; dy < 32; dy += 8) {
        const int i = i0 + ty + dy, o = o0 + tx;
        float v;
        if (r < RR) {
            float s = 0.f;
            #pragma unroll
            for (int b = 0; b < NBASE; b++)
                s += comp[r * NBASE + b] * basis[((long)b * 256 + i) * OUT + o];
            v = s;
        } else {
            v = root[(long)i * OUT + o];
        }
        t[ty + dy][tx] = f2bf(v);
    }
    __syncthreads();
    #pragma unroll
    for (int dy = 0; dy < 32; dy += 8)
        WT[(long)(n0 + ty + dy) * 256 + i0 + tx] = t[tx][ty + dy];
}

// ---- CSR build ----
__global__ void count_k(const int* __restrict__ dst, const int* __restrict__ et,
                        int* __restrict__ cnt) {
    int e = blockIdx.x * 256 + threadIdx.x;
    if (e < EE) atomicAdd(&cnt[dst[e] * RR + et[e]], 1);
}

__global__ void scan1_k(const int* __restrict__ cnt, int* __restrict__ incl,
                        int* __restrict__ bsum) {
    __shared__ int s[256];
    int i = blockIdx.x * 256 + threadIdx.x;
    int v = (i < NSEG) ? cnt[i] : 0;
    s[threadIdx.x] = v;
    __syncthreads();
    for (int off = 1; off < 256; off <<= 1) {
        int u = (threadIdx.x >= off) ? s[threadIdx.x - off] : 0;
        __syncthreads();
        s[threadIdx.x] += u;
        __syncthreads();
    }
    if (i < NSEG) incl[i] = s[threadIdx.x];
    if (threadIdx.x == 255) bsum[blockIdx.x] = s[255];
}

__global__ void scan2_k(int* __restrict__ bsum, int nb) {
    __shared__ int s[1024];
    int t = threadIdx.x;
    s[t] = (t < nb) ? bsum[t] : 0;
    __syncthreads();
    for (int off = 1; off < 1024; off <<= 1) {
        int u = (t >= off) ? s[t - off] : 0;
        __syncthreads();
        s[t] += u;
        __syncthreads();
    }
    if (t < nb) bsum[t] = s[t];
}

// scan3 + invc fused
__global__ void scan3_k(const int* __restrict__ cnt, const int* __restrict__ incl,
                        const int* __restrict__ bsum, int* __restrict__ row_ptr,
                        int* __restrict__ fillpos, float* __restrict__ invc) {
    int i = blockIdx.x * 256 + threadIdx.x;
    if (i >= NSEG) return;
    int c = cnt[i];
    int off = (blockIdx.x > 0) ? bsum[blockIdx.x - 1] : 0;
    int ex = off + incl[i] - c;
    row_ptr[i] = ex;
    fillpos[i] = ex;
    invc[i] = 1.f / (float)max(c, 1);
    if (i == 0) row_ptr[NSEG] = EE;
}

// per-edge: sorted slice offsets into XW1/XW2 + mean weight
__global__ void fill_k(const int* __restrict__ src, const int* __restrict__ dst,
                       const int* __restrict__ et, int* __restrict__ fillpos,
                       const float* __restrict__ invc,
                       int* __restrict__ eoff1, int* __restrict__ eoff2,
                       float* __restrict__ wgt) {
    int e = blockIdx.x * 256 + threadIdx.x;
    if (e < EE) {
        int s = src[e], t = et[e];
        int seg = dst[e] * RR + t;
        int p = atomicAdd(&fillpos[seg], 1);
        eoff1[p] = s * (17 * HIDF) + t * HIDF;
        eoff2[p] = s * (17 * OUTF) + t * OUTF;
        wgt[p] = invc[seg];
    }
}

// ---- X -> bf16 ----
__global__ void cvtbf_k(const float* __restrict__ X, short* __restrict__ Y) {
    int i = blockIdx.x * 256 + threadIdx.x;  // one per 4 cols
    if (i >= NN * 64) return;
    float4 v = *(const float4*)(X + (long)i * 4);
    s16x4 pk = { f2bf(v.x), f2bf(v.y), f2bf(v.z), f2bf(v.w) };
    *(s16x4*)&Y[(long)i * 4] = pk;
}

// ---- dense GEMM: XW[m][n] = sum_k A[m][k] * WT[n][k], K=256, bf16 out ----
// 128x64 tiles, BK=64, 4 waves as 2x2 (each 64 rows x 32 cols, FM=4 FN=2,
// acc=32 VGPR), single-buffer 24 KB LDS -> 6 blocks/CU. m-major XCD swizzle.
// XOR swizzle both sides: LDS slot s of row r holds global 16B-chunk s^(r&7).
// Epilogue: LDS restage (stride 68, bank-spread) -> full-line 16B/lane stores.
template <int NTOT>
__global__ __launch_bounds__(256, 6) void gemm_xw_k(const short* __restrict__ A,
                                                    const short* __restrict__ WT,
                                                    short* __restrict__ XW) {
    constexpr int NBN = NTOT / 64;
    __shared__ __align__(16) short smem[12288];  // As[0..8191], Bs[8192..12287]

    // bijective XCD swizzle (m204), m-major wgid
    const int nwg = gridDim.x;
    const int q = nwg >> 3, r = nwg & 7;
    const int orig = blockIdx.x;
    const int xcd = orig & 7, wi = orig >> 3;
    const int wgid = (xcd < r ? xcd * (q + 1) : r * (q + 1) + (xcd - r) * q) + wi;
    const int m0 = (wgid / NBN) * 128;
    const int n0 = (wgid % NBN) * 64;

    const int tid = threadIdx.x;
    const int lane = tid & 63;
    const int w = tid >> 6;
    const int wr = w >> 1, wc = w & 1;
    const int al = lane & 15;
    const int cl = lane >> 4;

    // staging source offsets (write-side swizzle; rows of 8 16B-chunks)
    int gsrcA[4];
    #pragma unroll
    for (int i = 0; i < 4; i++) {
        int ci = i * 256 + tid;
        int row = ci >> 3;
        gsrcA[i] = row * 256 + (((ci & 7) ^ (row & 7)) << 3);
    }
    int gsrcB[2];
    #pragma unroll
    for (int i = 0; i < 2; i++) {
        int ci = i * 256 + tid;
        int row = ci >> 3;
        gsrcB[i] = row * 256 + (((ci & 7) ^ (row & 7)) << 3);
    }

    // read offsets (same involution); LDS row = 64 shorts
    int aoff[4][2], boff[2][2];
    #pragma unroll
    for (int f = 0; f < 4; f++)
        #pragma unroll
        for (int k2 = 0; k2 < 2; k2++) {
            int ra = wr * 64 + f * 16 + al;
            aoff[f][k2] = (ra << 6) + ((((k2 << 2) | cl) ^ (ra & 7)) << 3);
        }
    #pragma unroll
    for (int f = 0; f < 2; f++)
        #pragma unroll
        for (int k2 = 0; k2 < 2; k2++) {
            int rb = wc * 32 + f * 16 + al;
            boff[f][k2] = (rb << 6) + ((((k2 << 2) | cl) ^ (rb & 7)) << 3);
        }

    f32x4 acc[4][2] = {};
    const short* abase = A + (long)m0 * 256;
    const short* bbase = WT + (long)n0 * 256;

    #pragma unroll
    for (int kk = 0; kk < 256; kk += 64) {
        #pragma unroll
        for (int i = 0; i < 4; i++)
            gl16(abase + kk + gsrcA[i], &smem[i * 2048 + w * 512]);
        #pragma unroll
        for (int i = 0; i < 2; i++)
            gl16(bbase + kk + gsrcB[i], &smem[8192 + i * 2048 + w * 512]);
        __syncthreads();

        bf16x8 a[4][2], b[2][2];
        #pragma unroll
        for (int f = 0; f < 4; f++)
            #pragma unroll
            for (int k2 = 0; k2 < 2; k2++)
                a[f][k2] = *(const bf16x8*)&smem[aoff[f][k2]];
        #pragma unroll
        for (int f = 0; f < 2; f++)
            #pragma unroll
            for (int k2 = 0; k2 < 2; k2++)
                b[f][k2] = *(const bf16x8*)&smem[8192 + boff[f][k2]];
        #pragma unroll
        for (int k2 = 0; k2 < 2; k2++)
            #pragma unroll
            for (int fm = 0; fm < 4; fm++)
                #pragma unroll
                for (int fn = 0; fn < 2; fn++)
                    acc[fm][fn] = __builtin_amdgcn_mfma_f32_16x16x32_bf16(
                        a[fm][k2], b[fn][k2], acc[fm][fn], 0, 0, 0);
        __syncthreads();
    }

    // epilogue stage 1: frags -> smem[row*68+col] (C/D: col=lane&15, row=(lane>>4)*4+j)
    #pragma unroll
    for (int fm = 0; fm < 4; fm++) {
        const int rowb = wr * 64 + fm * 16 + (cl << 2);
        #pragma unroll
        for (int fn = 0; fn < 2; fn++) {
            const int col = wc * 32 + fn * 16 + al;
            #pragma unroll
            for (int j = 0; j < 4; j++)
                smem[(rowb + j) * 68 + col] = f2bf(acc[fm][fn][j]);
        }
    }
    __syncthreads();

    // epilogue stage 2: coalesced stores, 128 rows x 128 B (aligned full lines)
    #pragma unroll
    for (int pass = 0; pass < 4; pass++) {
        int c = pass * 256 + tid;
        int row = c >> 3, qq = c & 7;
        uint4 v = *(const uint4*)&smem[row * 68 + qq * 8];
        *(uint4*)&XW[(long)(m0 + row) * NTOT + n0 + qq * 8] = v;
    }
}

// ---- per-node aggregate: out[n] = sum_edges wgt*XW[eoff] + XW[n,root] + bias ----
// one wave per node; each edge = one coalesced row-slice read; 4-way unrolled.
template <int OUT, bool L1>
__global__ void aggh_k(const int* __restrict__ rowp, const int* __restrict__ eoff,
                       const float* __restrict__ wgt, const short* __restrict__ XW,
                       const float* __restrict__ bias, short* __restrict__ Hout,
                       float* __restrict__ Fout) {
    constexpr int NTOT = 17 * OUT;
    const int n = (blockIdx.x * 256 + threadIdx.x) >> 6;
    const int lane = threadIdx.x & 63;
    if (n >= NN) return;
    const int b = rowp[n * 16], e = rowp[n * 16 + 16];

    if (L1) {
        float a0 = 0.f, a1 = 0.f, a2 = 0.f, a3 = 0.f;
        int j = b;
        for (; j + 3 < e; j += 4) {   // 4-way unroll: 4 gathers in flight
            s16x4 v0 = *(const s16x4*)&XW[(long)eoff[j] + lane * 4];
            s16x4 v1 = *(const s16x4*)&XW[(long)eoff[j + 1] + lane * 4];
            s16x4 v2 = *(const s16x4*)&XW[(long)eoff[j + 2] + lane * 4];
            s16x4 v3 = *(const s16x4*)&XW[(long)eoff[j + 3] + lane * 4];
            float w0 = wgt[j], w1 = wgt[j + 1], w2 = wgt[j + 2], w3 = wgt[j + 3];
            a0 += w0 * bf2f(v0.x) + w1 * bf2f(v1.x) + w2 * bf2f(v2.x) + w3 * bf2f(v3.x);
            a1 += w0 * bf2f(v0.y) + w1 * bf2f(v1.y) + w2 * bf2f(v2.y) + w3 * bf2f(v3.y);
            a2 += w0 * bf2f(v0.z) + w1 * bf2f(v1.z) + w2 * bf2f(v2.z) + w3 * bf2f(v3.z);
            a3 += w0 * bf2f(v0.w) + w1 * bf2f(v1.w) + w2 * bf2f(v2.w) + w3 * bf2f(v3.w);
        }
        for (; j < e; j++) {
            int o0 = eoff[j]; float w0 = wgt[j];
            s16x4 v0 = *(const s16x4*)&XW[(long)o0 + lane * 4];
            a0 += w0 * bf2f(v0.x); a1 += w0 * bf2f(v0.y);
            a2 += w0 * bf2f(v0.z); a3 += w0 * bf2f(v0.w);
        }
        s16x4 rt = *(const s16x4*)&XW[(long)n * NTOT + 16 * OUT + lane * 4];
        f32x4 bb = *(const f32x4*)&bias[lane * 4];
        a0 = fmaxf(a0 + bf2f(rt.x) + bb.x, 0.f);
        a1 = fmaxf(a1 + bf2f(rt.y) + bb.y, 0.f);
        a2 = fmaxf(a2 + bf2f(rt.z) + bb.z, 0.f);
        a3 = fmaxf(a3 + bf2f(rt.w) + bb.w, 0.f);
        s16x4 pk = { f2bf(a0), f2bf(a1), f2bf(a2), f2bf(a3) };
        *(s16x4*)&Hout[(long)n * OUT + lane * 4] = pk;
    } else {
        float a0 = 0.f, a1 = 0.f;
        int j = b;
        for (; j + 3 < e; j += 4) {
            unsigned v0 = *(const unsigned*)&XW[(long)eoff[j] + lane * 2];
            unsigned v1 = *(const unsigned*)&XW[(long)eoff[j + 1] + lane * 2];
            unsigned v2 = *(const unsigned*)&XW[(long)eoff[j + 2] + lane * 2];
            unsigned v3 = *(const unsigned*)&XW[(long)eoff[j + 3] + lane * 2];
            float w0 = wgt[j], w1 = wgt[j + 1], w2 = wgt[j + 2], w3 = wgt[j + 3];
            a0 += w0 * bf2f((short)(v0 & 0xffff)) + w1 * bf2f((short)(v1 & 0xffff))
                + w2 * bf2f((short)(v2 & 0xffff)) + w3 * bf2f((short)(v3 & 0xffff));
            a1 += w0 * bf2f((short)(v0 >> 16)) + w1 * bf2f((short)(v1 >> 16))
                + w2 * bf2f((short)(v2 >> 16)) + w3 * bf2f((short)(v3 >> 16));
        }
        for (; j < e; j++) {
            int o0 = eoff[j]; float w0 = wgt[j];
            unsigned v0 = *(const unsigned*)&XW[(long)o0 + lane * 2];
            a0 += w0 * bf2f((short)(v0 & 0xffff));
            a1 += w0 * bf2f((short)(v0 >> 16));
        }
        unsigned rt = *(const unsigned*)&XW[(long)n * NTOT + 16 * OUT + lane * 2];
        a0 += bf2f((short)(rt & 0xffff)) + bias[lane * 2];
        a1 += bf2f((short)(rt >> 16)) + bias[lane * 2 + 1];
        float2 st = { a0, a1 };
        *(float2*)&Fout[(long)n * OUT + lane * 2] = st;
    }
}

extern "C" void kernel_launch(void* const* d_in, const int* in_sizes, int n_in,
                              void* d_out, int out_size, void* d_ws, size_t ws_size,
                              hipStream_t stream) {
    const float* x      = (const float*)d_in[0];
    const int*   ei     = (const int*)d_in[1];
    const int*   et     = (const int*)d_in[2];
    const float* basis1 = (const float*)d_in[3];
    const float* comp1  = (const float*)d_in[4];
    const float* root1  = (const float*)d_in[5];
    const float* bias1  = (const float*)d_in[6];
    const float* basis2 = (const float*)d_in[7];
    const float* comp2  = (const float*)d_in[8];
    const float* root2  = (const float*)d_in[9];
    const float* bias2  = (const float*)d_in[10];
    const int* src = ei;
    const int* dst = ei + EE;

    char* p = (char*)d_ws;
    auto take = [&](size_t bytes) { char* q = p; p += (bytes + 255) & ~(size_t)255; return q; };
    short* XW    = (short*)take((size_t)MP * 17 * HIDF * 2); // 88 MB (layer2 reuses)
    short* WT1   = (short*)take((size_t)17 * HIDF * 256 * 2);// 2.23 MB
    short* WT2   = (short*)take((size_t)17 * OUTF * 256 * 2);// 1.11 MB
    short* Xbf   = (short*)take((size_t)MP * 256 * 2);       // 5.18 MB
    short* Hbf   = (short*)take((size_t)MP * 256 * 2);       // 5.18 MB
    int*   cnt   = (int*)take((size_t)NSEG * 4);
    float* invc  = (float*)take((size_t)NSEG * 4);
    int*   incl  = (int*)take((size_t)NSEG * 4);
    int*   rowp  = (int*)take((size_t)(NSEG + 1) * 4);
    int*   fpos  = (int*)take((size_t)NSEG * 4);
    int*   bsum  = (int*)take(1024 * 4);
    int*   eoff1 = (int*)take((size_t)EE * 4);
    int*   eoff2 = (int*)take((size_t)EE * 4);
    float* wgt   = (float*)take((size_t)EE * 4);

    const int NB1 = (NSEG + 255) / 256;  // 625

    hipMemsetAsync(cnt, 0, (size_t)NSEG * 4, stream);

    // weights
    {
        dim3 g1(256 / 32, 17 * HIDF / 32), g2(256 / 32, 17 * OUTF / 32);
        wtr_k<HIDF><<<g1, 256, 0, stream>>>(basis1, comp1, root1, WT1);
        wtr_k<OUTF><<<g2, 256, 0, stream>>>(basis2, comp2, root2, WT2);
    }

    // CSR + per-edge (offset, weight)
    count_k<<<(EE + 255) / 256, 256, 0, stream>>>(dst, et, cnt);
    scan1_k<<<NB1, 256, 0, stream>>>(cnt, incl, bsum);
    scan2_k<<<1, 1024, 0, stream>>>(bsum, NB1);
    scan3_k<<<NB1, 256, 0, stream>>>(cnt, incl, bsum, rowp, fpos, invc);
    fill_k<<<(EE + 255) / 256, 256, 0, stream>>>(src, dst, et, fpos, invc, eoff1, eoff2, wgt);

    // X -> bf16
    cvtbf_k<<<(NN * 64 + 255) / 256, 256, 0, stream>>>(x, Xbf);

    // layer 1: XW = X @ [W_r..., root]  (grid 79*68 = 5372), then per-node agg
    gemm_xw_k<17 * HIDF><<<(MP / 128) * (17 * HIDF / 64), 256, 0, stream>>>(Xbf, WT1, XW);
    aggh_k<HIDF, true><<<(NN * 64) / 256, 256, 0, stream>>>(rowp, eoff1, wgt, XW, bias1, Hbf, nullptr);

    // layer 2: XW2 = H @ [W_r..., root]  (grid 79*34 = 2686), then per-node agg
    gemm_xw_k<17 * OUTF><<<(MP / 128) * (17 * OUTF / 64), 256, 0, stream>>>(Hbf, WT2, XW);
    aggh_k<OUTF, false><<<(NN * 64) / 256, 256, 0, stream>>>(rowp, eoff2, wgt, XW, bias2, nullptr, (float*)d_out);
}

// Round 18
// 133.973 us; speedup vs baseline: 1.0919x; 1.0078x over previous
//
#include <hip/hip_runtime.h>
#include <hip/hip_bf16.h>

#define NN 10000
#define MP 10112        // 79*128 padded M
#define RR 16
#define NBASE 30
#define EE 160000
#define HIDF 256
#define OUTF 128
#define NSEG (NN * RR)

typedef __attribute__((ext_vector_type(8))) short bf16x8;
typedef __attribute__((ext_vector_type(4))) short s16x4;
typedef __attribute__((ext_vector_type(4))) float f32x4;

static __device__ __forceinline__ short f2bf(float f) {
    union { float f; unsigned u; } v; v.f = f;
    unsigned r = v.u + 0x7FFFu + ((v.u >> 16) & 1u);
    return (short)(r >> 16);
}
static __device__ __forceinline__ float bf2f(short s) {
    union { unsigned u; float f; } v;
    v.u = ((unsigned)(unsigned short)s) << 16;
    return v.f;
}
static __device__ __forceinline__ void gl16(const short* g, short* l) {
    __builtin_amdgcn_global_load_lds((const __attribute__((address_space(1))) void*)g,
                                     (__attribute__((address_space(3))) void*)l, 16, 0, 0);
}

// ---- custom zero for cnt (r18 single-variable test: replaces hipMemsetAsync,
// which shows 41-43us @ 15 GB/s in r15/r17 profiles for only 640 KB) ----
__global__ void zero_k(int4* __restrict__ p, int n4) {
    int i = blockIdx.x * 256 + threadIdx.x;
    if (i < n4) p[i] = make_int4(0, 0, 0, 0);
}

// ---- weight build: WT[n][i] bf16, n = r*OUT + o (r==16 -> root), stride 256 ----
template <int OUT>
__global__ void wtr_k(const float* __restrict__ basis, const float* __restrict__ comp,
                      const float* __restrict__ root, short* __restrict__ WT) {
    __shared__ short t[32][34];
    const int i0 = blockIdx.x * 32, n0 = blockIdx.y * 32;
    const int r = n0 / OUT, o0 = n0 % OUT;
    const int tx = threadIdx.x & 31, ty = threadIdx.x >> 5;  // ty 0..7
    #pragma unroll
    for (int dy = 0; dy < 32; dy += 8) {
        const int i = i0 + ty + dy, o = o0 + tx;
        float v;
        if (r < RR) {
            float s = 0.f;
            #pragma unroll
            for (int b = 0; b < NBASE; b++)
                s += comp[r * NBASE + b] * basis[((long)b * 256 + i) * OUT + o];
            v = s;
        } else {
            v = root[(long)i * OUT + o];
        }
        t[ty + dy][tx] = f2bf(v);
    }
    __syncthreads();
    #pragma unroll
    for (int dy = 0; dy < 32; dy += 8)
        WT[(long)(n0 + ty + dy) * 256 + i0 + tx] = t[tx][ty + dy];
}

// ---- CSR build ----
__global__ void count_k(const int* __restrict__ dst, const int* __restrict__ et,
                        int* __restrict__ cnt) {
    int e = blockIdx.x * 256 + threadIdx.x;
    if (e < EE) atomicAdd(&cnt[dst[e] * RR + et[e]], 1);
}

__global__ void scan1_k(const int* __restrict__ cnt, int* __restrict__ incl,
                        int* __restrict__ bsum) {
    __shared__ int s[256];
    int i = blockIdx.x * 256 + threadIdx.x;
    int v = (i < NSEG) ? cnt[i] : 0;
    s[threadIdx.x] = v;
    __syncthreads();
    for (int off = 1; off < 256; off <<= 1) {
        int u = (threadIdx.x >= off) ? s[threadIdx.x - off] : 0;
        __syncthreads();
        s[threadIdx.x] += u;
        __syncthreads();
    }
    if (i < NSEG) incl[i] = s[threadIdx.x];
    if (threadIdx.x == 255) bsum[blockIdx.x] = s[255];
}

__global__ void scan2_k(int* __restrict__ bsum, int nb) {
    __shared__ int s[1024];
    int t = threadIdx.x;
    s[t] = (t < nb) ? bsum[t] : 0;
    __syncthreads();
    for (int off = 1; off < 1024; off <<= 1) {
        int u = (t >= off) ? s[t - off] : 0;
        __syncthreads();
        s[t] += u;
        __syncthreads();
    }
    if (t < nb) bsum[t] = s[t];
}

// scan3 + invc fused
__global__ void scan3_k(const int* __restrict__ cnt, const int* __restrict__ incl,
                        const int* __restrict__ bsum, int* __restrict__ row_ptr,
                        int* __restrict__ fillpos, float* __restrict__ invc) {
    int i = blockIdx.x * 256 + threadIdx.x;
    if (i >= NSEG) return;
    int c = cnt[i];
    int off = (blockIdx.x > 0) ? bsum[blockIdx.x - 1] : 0;
    int ex = off + incl[i] - c;
    row_ptr[i] = ex;
    fillpos[i] = ex;
    invc[i] = 1.f / (float)max(c, 1);
    if (i == 0) row_ptr[NSEG] = EE;
}

// per-edge: sorted slice offsets into XW1/XW2 + mean weight
__global__ void fill_k(const int* __restrict__ src, const int* __restrict__ dst,
                       const int* __restrict__ et, int* __restrict__ fillpos,
                       const float* __restrict__ invc,
                       int* __restrict__ eoff1, int* __restrict__ eoff2,
                       float* __restrict__ wgt) {
    int e = blockIdx.x * 256 + threadIdx.x;
    if (e < EE) {
        int s = src[e], t = et[e];
        int seg = dst[e] * RR + t;
        int p = atomicAdd(&fillpos[seg], 1);
        eoff1[p] = s * (17 * HIDF) + t * HIDF;
        eoff2[p] = s * (17 * OUTF) + t * OUTF;
        wgt[p] = invc[seg];
    }
}

// ---- X -> bf16 ----
__global__ void cvtbf_k(const float* __restrict__ X, short* __restrict__ Y) {
    int i = blockIdx.x * 256 + threadIdx.x;  // one per 4 cols
    if (i >= NN * 64) return;
    float4 v = *(const float4*)(X + (long)i * 4);
    s16x4 pk = { f2bf(v.x), f2bf(v.y), f2bf(v.z), f2bf(v.w) };
    *(s16x4*)&Y[(long)i * 4] = pk;
}

// ---- dense GEMM: XW[m][n] = sum_k A[m][k] * WT[n][k], K=256, bf16 out ----
// 128x64 tiles, BK=64, 4 waves as 2x2 (each 64 rows x 32 cols, FM=4 FN=2,
// acc=32 VGPR), single-buffer 24 KB LDS -> 6 blocks/CU. m-major XCD swizzle.
// XOR swizzle both sides: LDS slot s of row r holds global 16B-chunk s^(r&7).
// Epilogue: LDS restage (stride 68, bank-spread) -> full-line 16B/lane stores.
template <int NTOT>
__global__ __launch_bounds__(256, 6) void gemm_xw_k(const short* __restrict__ A,
                                                    const short* __restrict__ WT,
                                                    short* __restrict__ XW) {
    constexpr int NBN = NTOT / 64;
    __shared__ __align__(16) short smem[12288];  // As[0..8191], Bs[8192..12287]

    // bijective XCD swizzle (m204), m-major wgid
    const int nwg = gridDim.x;
    const int q = nwg >> 3, r = nwg & 7;
    const int orig = blockIdx.x;
    const int xcd = orig & 7, wi = orig >> 3;
    const int wgid = (xcd < r ? xcd * (q + 1) : r * (q + 1) + (xcd - r) * q) + wi;
    const int m0 = (wgid / NBN) * 128;
    const int n0 = (wgid % NBN) * 64;

    const int tid = threadIdx.x;
    const int lane = tid & 63;
    const int w = tid >> 6;
    const int wr = w >> 1, wc = w & 1;
    const int al = lane & 15;
    const int cl = lane >> 4;

    // staging source offsets (write-side swizzle; rows of 8 16B-chunks)
    int gsrcA[4];
    #pragma unroll
    for (int i = 0; i < 4; i++) {
        int ci = i * 256 + tid;
        int row = ci >> 3;
        gsrcA[i] = row * 256 + (((ci & 7) ^ (row & 7)) << 3);
    }
    int gsrcB[2];
    #pragma unroll
    for (int i = 0; i < 2; i++) {
        int ci = i * 256 + tid;
        int row = ci >> 3;
        gsrcB[i] = row * 256 + (((ci & 7) ^ (row & 7)) << 3);
    }

    // read offsets (same involution); LDS row = 64 shorts
    int aoff[4][2], boff[2][2];
    #pragma unroll
    for (int f = 0; f < 4; f++)
        #pragma unroll
        for (int k2 = 0; k2 < 2; k2++) {
            int ra = wr * 64 + f * 16 + al;
            aoff[f][k2] = (ra << 6) + ((((k2 << 2) | cl) ^ (ra & 7)) << 3);
        }
    #pragma unroll
    for (int f = 0; f < 2; f++)
        #pragma unroll
        for (int k2 = 0; k2 < 2; k2++) {
            int rb = wc * 32 + f * 16 + al;
            boff[f][k2] = (rb << 6) + ((((k2 << 2) | cl) ^ (rb & 7)) << 3);
        }

    f32x4 acc[4][2] = {};
    const short* abase = A + (long)m0 * 256;
    const short* bbase = WT + (long)n0 * 256;

    #pragma unroll
    for (int kk = 0; kk < 256; kk += 64) {
        #pragma unroll
        for (int i = 0; i < 4; i++)
            gl16(abase + kk + gsrcA[i], &smem[i * 2048 + w * 512]);
        #pragma unroll
        for (int i = 0; i < 2; i++)
            gl16(bbase + kk + gsrcB[i], &smem[8192 + i * 2048 + w * 512]);
        __syncthreads();

        bf16x8 a[4][2], b[2][2];
        #pragma unroll
        for (int f = 0; f < 4; f++)
            #pragma unroll
            for (int k2 = 0; k2 < 2; k2++)
                a[f][k2] = *(const bf16x8*)&smem[aoff[f][k2]];
        #pragma unroll
        for (int f = 0; f < 2; f++)
            #pragma unroll
            for (int k2 = 0; k2 < 2; k2++)
                b[f][k2] = *(const bf16x8*)&smem[8192 + boff[f][k2]];
        #pragma unroll
        for (int k2 = 0; k2 < 2; k2++)
            #pragma unroll
            for (int fm = 0; fm < 4; fm++)
                #pragma unroll
                for (int fn = 0; fn < 2; fn++)
                    acc[fm][fn] = __builtin_amdgcn_mfma_f32_16x16x32_bf16(
                        a[fm][k2], b[fn][k2], acc[fm][fn], 0, 0, 0);
        __syncthreads();
    }

    // epilogue stage 1: frags -> smem[row*68+col] (C/D: col=lane&15, row=(lane>>4)*4+j)
    #pragma unroll
    for (int fm = 0; fm < 4; fm++) {
        const int rowb = wr * 64 + fm * 16 + (cl << 2);
        #pragma unroll
        for (int fn = 0; fn < 2; fn++) {
            const int col = wc * 32 + fn * 16 + al;
            #pragma unroll
            for (int j = 0; j < 4; j++)
                smem[(rowb + j) * 68 + col] = f2bf(acc[fm][fn][j]);
        }
    }
    __syncthreads();

    // epilogue stage 2: coalesced stores, 128 rows x 128 B (aligned full lines)
    #pragma unroll
    for (int pass = 0; pass < 4; pass++) {
        int c = pass * 256 + tid;
        int row = c >> 3, qq = c & 7;
        uint4 v = *(const uint4*)&smem[row * 68 + qq * 8];
        *(uint4*)&XW[(long)(m0 + row) * NTOT + n0 + qq * 8] = v;
    }
}

// ---- per-node aggregate: out[n] = sum_edges wgt*XW[eoff] + XW[n,root] + bias ----
// one wave per node; each edge = one coalesced row-slice read; 4-way unrolled.
template <int OUT, bool L1>
__global__ void aggh_k(const int* __restrict__ rowp, const int* __restrict__ eoff,
                       const float* __restrict__ wgt, const short* __restrict__ XW,
                       const float* __restrict__ bias, short* __restrict__ Hout,
                       float* __restrict__ Fout) {
    constexpr int NTOT = 17 * OUT;
    const int n = (blockIdx.x * 256 + threadIdx.x) >> 6;
    const int lane = threadIdx.x & 63;
    if (n >= NN) return;
    const int b = rowp[n * 16], e = rowp[n * 16 + 16];

    if (L1) {
        float a0 = 0.f, a1 = 0.f, a2 = 0.f, a3 = 0.f;
        int j = b;
        for (; j + 3 < e; j += 4) {   // 4-way unroll: 4 gathers in flight
            s16x4 v0 = *(const s16x4*)&XW[(long)eoff[j] + lane * 4];
            s16x4 v1 = *(const s16x4*)&XW[(long)eoff[j + 1] + lane * 4];
            s16x4 v2 = *(const s16x4*)&XW[(long)eoff[j + 2] + lane * 4];
            s16x4 v3 = *(const s16x4*)&XW[(long)eoff[j + 3] + lane * 4];
            float w0 = wgt[j], w1 = wgt[j + 1], w2 = wgt[j + 2], w3 = wgt[j + 3];
            a0 += w0 * bf2f(v0.x) + w1 * bf2f(v1.x) + w2 * bf2f(v2.x) + w3 * bf2f(v3.x);
            a1 += w0 * bf2f(v0.y) + w1 * bf2f(v1.y) + w2 * bf2f(v2.y) + w3 * bf2f(v3.y);
            a2 += w0 * bf2f(v0.z) + w1 * bf2f(v1.z) + w2 * bf2f(v2.z) + w3 * bf2f(v3.z);
            a3 += w0 * bf2f(v0.w) + w1 * bf2f(v1.w) + w2 * bf2f(v2.w) + w3 * bf2f(v3.w);
        }
        for (; j < e; j++) {
            int o0 = eoff[j]; float w0 = wgt[j];
            s16x4 v0 = *(const s16x4*)&XW[(long)o0 + lane * 4];
            a0 += w0 * bf2f(v0.x); a1 += w0 * bf2f(v0.y);
            a2 += w0 * bf2f(v0.z); a3 += w0 * bf2f(v0.w);
        }
        s16x4 rt = *(const s16x4*)&XW[(long)n * NTOT + 16 * OUT + lane * 4];
        f32x4 bb = *(const f32x4*)&bias[lane * 4];
        a0 = fmaxf(a0 + bf2f(rt.x) + bb.x, 0.f);
        a1 = fmaxf(a1 + bf2f(rt.y) + bb.y, 0.f);
        a2 = fmaxf(a2 + bf2f(rt.z) + bb.z, 0.f);
        a3 = fmaxf(a3 + bf2f(rt.w) + bb.w, 0.f);
        s16x4 pk = { f2bf(a0), f2bf(a1), f2bf(a2), f2bf(a3) };
        *(s16x4*)&Hout[(long)n * OUT + lane * 4] = pk;
    } else {
        float a0 = 0.f, a1 = 0.f;
        int j = b;
        for (; j + 3 < e; j += 4) {
            unsigned v0 = *(const unsigned*)&XW[(long)eoff[j] + lane * 2];
            unsigned v1 = *(const unsigned*)&XW[(long)eoff[j + 1] + lane * 2];
            unsigned v2 = *(const unsigned*)&XW[(long)eoff[j + 2] + lane * 2];
            unsigned v3 = *(const unsigned*)&XW[(long)eoff[j + 3] + lane * 2];
            float w0 = wgt[j], w1 = wgt[j + 1], w2 = wgt[j + 2], w3 = wgt[j + 3];
            a0 += w0 * bf2f((short)(v0 & 0xffff)) + w1 * bf2f((short)(v1 & 0xffff))
                + w2 * bf2f((short)(v2 & 0xffff)) + w3 * bf2f((short)(v3 & 0xffff));
            a1 += w0 * bf2f((short)(v0 >> 16)) + w1 * bf2f((short)(v1 >> 16))
                + w2 * bf2f((short)(v2 >> 16)) + w3 * bf2f((short)(v3 >> 16));
        }
        for (; j < e; j++) {
            int o0 = eoff[j]; float w0 = wgt[j];
            unsigned v0 = *(const unsigned*)&XW[(long)o0 + lane * 2];
            a0 += w0 * bf2f((short)(v0 & 0xffff));
            a1 += w0 * bf2f((short)(v0 >> 16));
        }
        unsigned rt = *(const unsigned*)&XW[(long)n * NTOT + 16 * OUT + lane * 2];
        a0 += bf2f((short)(rt & 0xffff)) + bias[lane * 2];
        a1 += bf2f((short)(rt >> 16)) + bias[lane * 2 + 1];
        float2 st = { a0, a1 };
        *(float2*)&Fout[(long)n * OUT + lane * 2] = st;
    }
}

extern "C" void kernel_launch(void* const* d_in, const int* in_sizes, int n_in,
                              void* d_out, int out_size, void* d_ws, size_t ws_size,
                              hipStream_t stream) {
    const float* x      = (const float*)d_in[0];
    const int*   ei     = (const int*)d_in[1];
    const int*   et     = (const int*)d_in[2];
    const float* basis1 = (const float*)d_in[3];
    const float* comp1  = (const float*)d_in[4];
    const float* root1  = (const float*)d_in[5];
    const float* bias1  = (const float*)d_in[6];
    const float* basis2 = (const float*)d_in[7];
    const float* comp2  = (const float*)d_in[8];
    const float* root2  = (const float*)d_in[9];
    const float* bias2  = (const float*)d_in[10];
    const int* src = ei;
    const int* dst = ei + EE;

    char* p = (char*)d_ws;
    auto take = [&](size_t bytes) { char* q = p; p += (bytes + 255) & ~(size_t)255; return q; };
    short* XW    = (short*)take((size_t)MP * 17 * HIDF * 2); // 88 MB (layer2 reuses)
    short* WT1   = (short*)take((size_t)17 * HIDF * 256 * 2);// 2.23 MB
    short* WT2   = (short*)take((size_t)17 * OUTF * 256 * 2);// 1.11 MB
    short* Xbf   = (short*)take((size_t)MP * 256 * 2);       // 5.18 MB
    short* Hbf   = (short*)take((size_t)MP * 256 * 2);       // 5.18 MB
    int*   cnt   = (int*)take((size_t)NSEG * 4);
    float* invc  = (float*)take((size_t)NSEG * 4);
    int*   incl  = (int*)take((size_t)NSEG * 4);
    int*   rowp  = (int*)take((size_t)(NSEG + 1) * 4);
    int*   fpos  = (int*)take((size_t)NSEG * 4);
    int*   bsum  = (int*)take(1024 * 4);
    int*   eoff1 = (int*)take((size_t)EE * 4);
    int*   eoff2 = (int*)take((size_t)EE * 4);
    float* wgt   = (float*)take((size_t)EE * 4);

    const int NB1 = (NSEG + 255) / 256;  // 625

    // zero cnt via custom kernel (r18 ablation of the 41us hipMemsetAsync anomaly)
    zero_k<<<(NSEG / 4 + 255) / 256, 256, 0, stream>>>((int4*)cnt, NSEG / 4);

    // weights
    {
        dim3 g1(256 / 32, 17 * HIDF / 32), g2(256 / 32, 17 * OUTF / 32);
        wtr_k<HIDF><<<g1, 256, 0, stream>>>(basis1, comp1, root1, WT1);
        wtr_k<OUTF><<<g2, 256, 0, stream>>>(basis2, comp2, root2, WT2);
    }

    // CSR + per-edge (offset, weight)
    count_k<<<(EE + 255) / 256, 256, 0, stream>>>(dst, et, cnt);
    scan1_k<<<NB1, 256, 0, stream>>>(cnt, incl, bsum);
    scan2_k<<<1, 1024, 0, stream>>>(bsum, NB1);
    scan3_k<<<NB1, 256, 0, stream>>>(cnt, incl, bsum, rowp, fpos, invc);
    fill_k<<<(EE + 255) / 256, 256, 0, stream>>>(src, dst, et, fpos, invc, eoff1, eoff2, wgt);

    // X -> bf16
    cvtbf_k<<<(NN * 64 + 255) / 256, 256, 0, stream>>>(x, Xbf);

    // layer 1: XW = X @ [W_r..., root]  (grid 79*68 = 5372), then per-node agg
    gemm_xw_k<17 * HIDF><<<(MP / 128) * (17 * HIDF / 64), 256, 0, stream>>>(Xbf, WT1, XW);
    aggh_k<HIDF, true><<<(NN * 64) / 256, 256, 0, stream>>>(rowp, eoff1, wgt, XW, bias1, Hbf, nullptr);

    // layer 2: XW2 = H @ [W_r..., root]  (grid 79*34 = 2686), then per-node agg
    gemm_xw_k<17 * OUTF><<<(MP / 128) * (17 * OUTF / 64), 256, 0, stream>>>(Hbf, WT2, XW);
    aggh_k<OUTF, false><<<(NN * 64) / 256, 256, 0, stream>>>(rowp, eoff2, wgt, XW, bias2, nullptr, (float*)d_out);
}